// Round 7
// baseline (190.260 us; speedup 1.0000x reference)
//
#include <hip/hip_runtime.h>
#include <hip/hip_bf16.h>

using short8  = __attribute__((ext_vector_type(8))) short;
using ushort8 = __attribute__((ext_vector_type(8))) unsigned short;
using f32x4   = __attribute__((ext_vector_type(4))) float;

__device__ inline void gload_lds16(const void* g, void* lds) {
    __builtin_amdgcn_global_load_lds(
        (const __attribute__((address_space(1))) void*)g,
        (__attribute__((address_space(3))) void*)lds, 16, 0, 0);
}

// 16-lane reduction via DPP row_ror (pure VALU, no LDS pipe).
template <int CTRL>
__device__ inline float dpp_add(float x) {
    int v = __builtin_amdgcn_update_dpp(0, __float_as_int(x), CTRL, 0xf, 0xf, true);
    return x + __int_as_float(v);
}
__device__ inline float reduce16(float x) {
    x = dpp_add<0x121>(x);  // row_ror:1
    x = dpp_add<0x122>(x);  // row_ror:2
    x = dpp_add<0x124>(x);  // row_ror:4
    x = dpp_add<0x128>(x);  // row_ror:8
    return x;
}

// Kernel 0: suffix-sum table ST[k][j] = sum_{q>=k} E[j][q].
__global__ __launch_bounds__(256) void suffix_kernel(const float* __restrict__ E,
                                                     float* __restrict__ ST, int m) {
    int j = blockIdx.x;
    int k = threadIdx.x;
    int lane = k & 63, w = k >> 6;
    __shared__ float wtot[4];
    float v = (k < m) ? E[(size_t)j * m + k] : 0.f;
    #pragma unroll
    for (int off = 1; off < 64; off <<= 1) {
        float o = __shfl_down(v, off);
        if (lane + off < 64) v += o;
    }
    if (lane == 0) wtot[w] = v;
    __syncthreads();
    float add = 0.f;
    #pragma unroll
    for (int w2 = 0; w2 < 4; ++w2)
        if (w2 > w) add += wtot[w2];
    v += add;
    if (k < m) ST[(size_t)k * m + j] = v;
}

// Kernel 1: per-row prep. 16 lanes per row (4 rows/wave). Assumes m == 256, B % 16 == 0.
__global__ __launch_bounds__(256) void prep_kernel(
    const float* __restrict__ z, const float* __restrict__ t,
    const float* __restrict__ e, const float* __restrict__ log_tau,
    const float* __restrict__ E, const float* __restrict__ L,
    const float* __restrict__ ST,
    __hip_bfloat16* __restrict__ hz, __hip_bfloat16* __restrict__ hy,
    float* __restrict__ g, float* __restrict__ acc, int B, int m)
{
    const int tid = threadIdx.x;
    const int row = blockIdx.x * 16 + (tid >> 4);
    const int sub = tid & 15;

    float tv = t[row], ev = e[row];

    // searchsorted (side='left'): first idx with L[idx] >= t
    int lo = 0, hi = m;
    while (lo < hi) { int mid = (lo + hi) >> 1; if (L[mid] < tv) lo = mid + 1; else hi = mid; }
    int idx = lo;
    if (idx == 0) idx = 1;
    if (idx == m) idx = m - 1;

    float Llo = L[idx - 1], Lhi = L[idx];
    float w    = (tv - Llo) / (Lhi - Llo);
    float invd = 1.0f / (float)(m - idx);
    float invtau = expf(-0.5f * log_tau[0]);   // 1/sqrt(exp(log_tau))

    const int j0 = sub * 16;
    f32x4 zv[4], El4[4], Eh4[4], Sc4[4], yv[4];
    #pragma unroll
    for (int q = 0; q < 4; ++q) {
        zv[q]  = *(const f32x4*)&z [(size_t)row * m + j0 + q * 4];
        El4[q] = *(const f32x4*)&E [(size_t)(idx - 1) * m + j0 + q * 4];
        Eh4[q] = *(const f32x4*)&E [(size_t)idx * m + j0 + q * 4];
        Sc4[q] = *(const f32x4*)&ST[(size_t)idx * m + j0 + q * 4];
    }
    float ssy = 0.f, ssz = 0.f;
    #pragma unroll
    for (int q = 0; q < 4; ++q)
        #pragma unroll
        for (int p = 0; p < 4; ++p) {
            float yint = El4[q][p] + (Eh4[q][p] - El4[q][p]) * w;
            float ycen = Sc4[q][p] * invd;
            float y = yint * ev + ycen * (1.f - ev);
            yv[q][p] = y; ssy += y * y;
            ssz += zv[q][p] * zv[q][p];
        }
    ssy = reduce16(ssy);
    ssz = reduce16(ssz);
    float sy = invtau / fmaxf(sqrtf(ssy), 1e-12f);
    float sz = invtau / fmaxf(sqrtf(ssz), 1e-12f);

    float gp = 0.f;
    ushort8 oy[2], oz[2];
    #pragma unroll
    for (int q = 0; q < 4; ++q)
        #pragma unroll
        for (int p = 0; p < 4; ++p) {
            float hyv = yv[q][p] * sy, hzv = zv[q][p] * sz;
            gp += hyv * hzv;
            __hip_bfloat16 hb = __float2bfloat16(hyv);
            __hip_bfloat16 zb = __float2bfloat16(hzv);
            oy[q >> 1][(q & 1) * 4 + p] = *reinterpret_cast<unsigned short*>(&hb);
            oz[q >> 1][(q & 1) * 4 + p] = *reinterpret_cast<unsigned short*>(&zb);
        }
    *(ushort8*)&hy[(size_t)row * m + j0]     = oy[0];
    *(ushort8*)&hy[(size_t)row * m + j0 + 8] = oy[1];
    *(ushort8*)&hz[(size_t)row * m + j0]     = oz[0];
    *(ushort8*)&hz[(size_t)row * m + j0 + 8] = oz[1];
    gp = reduce16(gp);
    if (sub == 0) { g[row] = gp; acc[row] = 0.f; }
}

// Kernel 2: resident-A GEMM + exp + row sums.
// 256 blocks (1/CU), 512 threads (8 waves, 2M x 4N, per-wave 128x64).
// Block by = bid>>3 owns A-panel rows [by*256, by*256+256) staged ONCE in 128KB LDS
// (XOR-swizzled chunks, conflict-free ds_read_b128). It computes 4 consecutive
// 256-col tiles, B fragments read directly from global (L2-hot, 64B-coalesced,
// double-buffered registers). Single barrier after staging; waves free-run.
__global__ __launch_bounds__(512, 2) void gemm_lse_kernel(
    const __hip_bfloat16* __restrict__ hz, const __hip_bfloat16* __restrict__ hy,
    float* __restrict__ row_acc, int Brows, int K)
{
    __shared__ __hip_bfloat16 Apanel[256 * 256];   // 128 KB

    const int tid  = threadIdx.x;
    const int wid  = tid >> 6;   // 0..7
    const int lane = tid & 63;
    const int wm   = wid >> 2;   // 0..1
    const int wn   = wid & 3;    // 0..3
    const int lm   = lane & 15, lk = lane >> 4;

    const int by  = blockIdx.x >> 3;        // 0..31
    const int bxg = (blockIdx.x & 7) * 4;   // first col-tile (tile units)
    const int row0 = by * 256;

    // ---- Stage A panel: 128 KB, 16 wave-instructions per wave ----
    // Chunk C (16B) lives at LDS linear pos C; content = global chunk q = (C&31)^(r&7),
    // r = C>>5. Read side applies the same XOR -> round-trips (rule 21).
    #pragma unroll
    for (int s = 0; s < 16; ++s) {
        int Cbase = (s * 8 + wid) * 64;          // wave-uniform
        int C = Cbase + lane;
        int r = C >> 5;
        int q = (C & 31) ^ (r & 7);
        gload_lds16(hz + (((size_t)(row0 + r)) << 8) + (q << 3),
                    (void*)&Apanel[(size_t)Cbase * 8]);
    }
    __syncthreads();   // drains vmcnt; Apanel read-only afterwards

    short8 a[8], b[2][4];

#define LOADB(DST, BASE, KB)                                                      \
    { _Pragma("unroll")                                                           \
      for (int ni = 0; ni < 4; ++ni)                                              \
          b[DST][ni] = *(const short8*)&(BASE)[(size_t)(ni * 16 + lm) * 256 +     \
                                               (KB) * 32 + lk * 8]; }

    // preload b[0] for tile 0, kb 0
    {
        const __hip_bfloat16* hy0 = hy + (size_t)(bxg * 256 + wn * 64) * 256;
        LOADB(0, hy0, 0)
    }

    const int lg = lane >> 4;
    for (int tx = 0; tx < 4; ++tx) {
        const __hip_bfloat16* hyc = hy + (size_t)((bxg + tx) * 256 + wn * 64) * 256;
        const __hip_bfloat16* hyn = hy + (size_t)((bxg + (tx < 3 ? tx + 1 : tx)) * 256 + wn * 64) * 256;

        f32x4 acc[8][4];
        #pragma unroll
        for (int i = 0; i < 8; ++i)
            #pragma unroll
            for (int j = 0; j < 4; ++j)
                acc[i][j] = (f32x4){0.f, 0.f, 0.f, 0.f};

        #pragma unroll
        for (int kb = 0; kb < 8; ++kb) {
            const int cbuf = kb & 1, nb = cbuf ^ 1;
            // 1. issue next-slice B loads (consumed next iteration / next tile)
            if (kb < 7) { LOADB(nb, hyc, kb + 1) }
            else        { LOADB(nb, hyn, 0) }
            // 2. A fragments from LDS (swizzled)
            #pragma unroll
            for (int mi = 0; mi < 8; ++mi) {
                int rt = wm * 128 + mi * 16 + lm;
                a[mi] = *(const short8*)&Apanel[(size_t)rt * 256 +
                                                (((kb * 4 + lk) ^ (rt & 7)) << 3)];
            }
            // 3. MFMA
            #pragma unroll
            for (int mi = 0; mi < 8; ++mi)
                #pragma unroll
                for (int ni = 0; ni < 4; ++ni)
                    acc[mi][ni] = __builtin_amdgcn_mfma_f32_16x16x32_bf16(
                        a[mi], b[cbuf][ni], acc[mi][ni], 0, 0, 0);
        }

        // Epilogue: exp + row sums (DPP reduce, no LDS pipe).
        // C/D: col = lane&15, row = (lane>>4)*4 + reg.
        #pragma unroll
        for (int mi = 0; mi < 8; ++mi) {
            float rs[4] = {0.f, 0.f, 0.f, 0.f};
            #pragma unroll
            for (int ni = 0; ni < 4; ++ni) {
                #pragma unroll
                for (int r = 0; r < 4; ++r) rs[r] += __expf(acc[mi][ni][r]);
            }
            #pragma unroll
            for (int r = 0; r < 4; ++r) {
                float s = reduce16(rs[r]);
                if (lm == 0)
                    unsafeAtomicAdd(&row_acc[row0 + wm * 128 + mi * 16 + lg * 4 + r], s);
            }
        }
    }
#undef LOADB
}

// Kernel 3: out = clip(log(acc) - g - log(B), -5, 15)
__global__ void finalize_kernel(const float* __restrict__ acc, const float* __restrict__ g,
                                float* __restrict__ out, int B) {
    int i = blockIdx.x * 256 + threadIdx.x;
    if (i < B) {
        float v = logf(acc[i]) - g[i] - logf((float)B);
        out[i] = fminf(fmaxf(v, -5.f), 15.f);
    }
}

extern "C" void kernel_launch(void* const* d_in, const int* in_sizes, int n_in,
                              void* d_out, int out_size, void* d_ws, size_t ws_size,
                              hipStream_t stream) {
    const float* z       = (const float*)d_in[0];
    const float* t       = (const float*)d_in[1];
    const float* e       = (const float*)d_in[2];
    const float* log_tau = (const float*)d_in[3];
    const float* E       = (const float*)d_in[4];
    const float* L       = (const float*)d_in[5];
    float* out = (float*)d_out;

    const int B = in_sizes[1];   // 8192
    const int m = in_sizes[5];   // 256

    char* w = (char*)d_ws;
    __hip_bfloat16* hz = (__hip_bfloat16*)w;                 // B*m bf16
    __hip_bfloat16* hy = hz + (size_t)B * m;                 // B*m bf16
    float* ST   = (float*)(hy + (size_t)B * m);              // m*m f32
    float* g    = ST + (size_t)m * m;                        // B f32
    float* acc  = g + B;                                     // B f32

    suffix_kernel<<<m, 256, 0, stream>>>(E, ST, m);
    prep_kernel<<<B / 16, 256, 0, stream>>>(z, t, e, log_tau, E, L, ST, hz, hy, g, acc, B, m);
    gemm_lse_kernel<<<256, 512, 0, stream>>>(hz, hy, acc, B, m);
    finalize_kernel<<<(B + 255) / 256, 256, 0, stream>>>(acc, g, out, B);
}

// Round 8
// 131.357 us; speedup vs baseline: 1.4484x; 1.4484x over previous
//
#include <hip/hip_runtime.h>
#include <hip/hip_bf16.h>

using short8  = __attribute__((ext_vector_type(8))) short;
using ushort8 = __attribute__((ext_vector_type(8))) unsigned short;
using f32x4   = __attribute__((ext_vector_type(4))) float;

__device__ inline void gload_lds16(const void* g, void* lds) {
    __builtin_amdgcn_global_load_lds(
        (const __attribute__((address_space(1))) void*)g,
        (__attribute__((address_space(3))) void*)lds, 16, 0, 0);
}

// 16-lane reduction via DPP row_ror (pure VALU, no LDS pipe).
template <int CTRL>
__device__ inline float dpp_add(float x) {
    int v = __builtin_amdgcn_update_dpp(0, __float_as_int(x), CTRL, 0xf, 0xf, true);
    return x + __int_as_float(v);
}
__device__ inline float reduce16(float x) {
    x = dpp_add<0x121>(x);
    x = dpp_add<0x122>(x);
    x = dpp_add<0x124>(x);
    x = dpp_add<0x128>(x);
    return x;
}

// Kernel 0: suffix-sum table ST[k][j] = sum_{q>=k} E[j][q].
__global__ __launch_bounds__(256) void suffix_kernel(const float* __restrict__ E,
                                                     float* __restrict__ ST, int m) {
    int j = blockIdx.x;
    int k = threadIdx.x;
    int lane = k & 63, w = k >> 6;
    __shared__ float wtot[4];
    float v = (k < m) ? E[(size_t)j * m + k] : 0.f;
    #pragma unroll
    for (int off = 1; off < 64; off <<= 1) {
        float o = __shfl_down(v, off);
        if (lane + off < 64) v += o;
    }
    if (lane == 0) wtot[w] = v;
    __syncthreads();
    float add = 0.f;
    #pragma unroll
    for (int w2 = 0; w2 < 4; ++w2)
        if (w2 > w) add += wtot[w2];
    v += add;
    if (k < m) ST[(size_t)k * m + j] = v;
}

// Kernel 1: per-row prep. 16 lanes per row (4 rows/wave). Assumes m == 256, B % 16 == 0.
__global__ __launch_bounds__(256) void prep_kernel(
    const float* __restrict__ z, const float* __restrict__ t,
    const float* __restrict__ e, const float* __restrict__ log_tau,
    const float* __restrict__ E, const float* __restrict__ L,
    const float* __restrict__ ST,
    __hip_bfloat16* __restrict__ hz, __hip_bfloat16* __restrict__ hy,
    float* __restrict__ g, float* __restrict__ acc, int B, int m)
{
    const int tid = threadIdx.x;
    const int row = blockIdx.x * 16 + (tid >> 4);
    const int sub = tid & 15;

    float tv = t[row], ev = e[row];

    int lo = 0, hi = m;
    while (lo < hi) { int mid = (lo + hi) >> 1; if (L[mid] < tv) lo = mid + 1; else hi = mid; }
    int idx = lo;
    if (idx == 0) idx = 1;
    if (idx == m) idx = m - 1;

    float Llo = L[idx - 1], Lhi = L[idx];
    float w    = (tv - Llo) / (Lhi - Llo);
    float invd = 1.0f / (float)(m - idx);
    float invtau = expf(-0.5f * log_tau[0]);

    const int j0 = sub * 16;
    f32x4 zv[4], El4[4], Eh4[4], Sc4[4], yv[4];
    #pragma unroll
    for (int q = 0; q < 4; ++q) {
        zv[q]  = *(const f32x4*)&z [(size_t)row * m + j0 + q * 4];
        El4[q] = *(const f32x4*)&E [(size_t)(idx - 1) * m + j0 + q * 4];
        Eh4[q] = *(const f32x4*)&E [(size_t)idx * m + j0 + q * 4];
        Sc4[q] = *(const f32x4*)&ST[(size_t)idx * m + j0 + q * 4];
    }
    float ssy = 0.f, ssz = 0.f;
    #pragma unroll
    for (int q = 0; q < 4; ++q)
        #pragma unroll
        for (int p = 0; p < 4; ++p) {
            float yint = El4[q][p] + (Eh4[q][p] - El4[q][p]) * w;
            float ycen = Sc4[q][p] * invd;
            float y = yint * ev + ycen * (1.f - ev);
            yv[q][p] = y; ssy += y * y;
            ssz += zv[q][p] * zv[q][p];
        }
    ssy = reduce16(ssy);
    ssz = reduce16(ssz);
    float sy = invtau / fmaxf(sqrtf(ssy), 1e-12f);
    float sz = invtau / fmaxf(sqrtf(ssz), 1e-12f);

    float gp = 0.f;
    ushort8 oy[2], oz[2];
    #pragma unroll
    for (int q = 0; q < 4; ++q)
        #pragma unroll
        for (int p = 0; p < 4; ++p) {
            float hyv = yv[q][p] * sy, hzv = zv[q][p] * sz;
            gp += hyv * hzv;
            __hip_bfloat16 hb = __float2bfloat16(hyv);
            __hip_bfloat16 zb = __float2bfloat16(hzv);
            oy[q >> 1][(q & 1) * 4 + p] = *reinterpret_cast<unsigned short*>(&hb);
            oz[q >> 1][(q & 1) * 4 + p] = *reinterpret_cast<unsigned short*>(&zb);
        }
    *(ushort8*)&hy[(size_t)row * m + j0]     = oy[0];
    *(ushort8*)&hy[(size_t)row * m + j0 + 8] = oy[1];
    *(ushort8*)&hz[(size_t)row * m + j0]     = oz[0];
    *(ushort8*)&hz[(size_t)row * m + j0 + 8] = oz[1];
    gp = reduce16(gp);
    if (sub == 0) { g[row] = gp; acc[row] = 0.f; }
}

// Kernel 2: fused sim = hz @ hy^T + exp + row partial sums.
// 256x256 tile, 8 waves (2M x 4N, per-wave 128x64). BK=32, K=256 -> 8 K-tiles.
// LDS: 4-buffer ring (4 x 16KB per operand = 128 KB), prefetch depth 3 tiles,
// counted vmcnt(8) steady (never drains mid-loop). 2 phases/tile, each
// {ds_read ; 2x gload trickle ; barrier ; setprio + 16 MFMA ; barrier}.
// Chunk swizzle f(r) = (r&3)^((r>>2)&3) applied on BOTH source and read (rule 21);
// gives 2-way (free) LDS read conflicts at 64B row stride.
__global__ __launch_bounds__(512, 2) void gemm_lse_kernel(
    const __hip_bfloat16* __restrict__ hz, const __hip_bfloat16* __restrict__ hy,
    float* __restrict__ row_acc, int Brows, int K)
{
    __shared__ __hip_bfloat16 As[4][256 * 32];
    __shared__ __hip_bfloat16 Bs[4][256 * 32];

    const int tid  = threadIdx.x;
    const int wid  = tid >> 6;
    const int lane = tid & 63;
    const int wm   = wid >> 2;   // 0..1
    const int wn   = wid & 3;    // 0..3
    const int lm   = lane & 15, lk = lane >> 4;

    int bx = blockIdx.x, by = blockIdx.y;
    if (gridDim.x == 32 && gridDim.y == 32) {
        int orig = by * 32 + bx;
        int xcd = orig & 7, pos = orig >> 3;
        by = (xcd << 2) | (pos & 3);
        bx = pos >> 2;
    }
    const int row0 = by * 256, col0 = bx * 256;

    f32x4 acc[8][4];
    #pragma unroll
    for (int i = 0; i < 8; ++i)
        #pragma unroll
        for (int j = 0; j < 4; ++j)
            acc[i][j] = (f32x4){0.f, 0.f, 0.f, 0.f};

#define FXOR(r) ((((r) & 3)) ^ (((r) >> 2) & 3))

    // Staging: tile = 256 rows x 32 K x 2B = 16KB per operand = 1024 x 16B chunks.
    // Thread covers chunks C0 = tid (rows 0..127) and C1 = 512 + tid (rows 128..255).
    // LDS dest linear at chunk C; global source chunk q = (C&3) ^ f(r)  (inverse swizzle).
    const int r0s = tid >> 2;              // row for C0
    const int q0  = (tid & 3) ^ FXOR(r0s);
    const int r1s = 128 + (tid >> 2);      // row for C1
    const int q1  = (tid & 3) ^ FXOR(r1s);
    const int ldsc0 = (wid * 64) * 8;          // element offset of C-base, load 0
    const int ldsc1 = (512 + wid * 64) * 8;    // load 1

#define STAGE_A(SB, kt)                                                           \
    do {                                                                          \
        gload_lds16(hz + (size_t)(row0 + r0s) * 256 + (kt) * 32 + q0 * 8,         \
                    (void*)&As[SB][ldsc0]);                                       \
        gload_lds16(hz + (size_t)(row0 + r1s) * 256 + (kt) * 32 + q1 * 8,         \
                    (void*)&As[SB][ldsc1]);                                       \
    } while (0)
#define STAGE_B(SB, kt)                                                           \
    do {                                                                          \
        gload_lds16(hy + (size_t)(col0 + r0s) * 256 + (kt) * 32 + q0 * 8,         \
                    (void*)&Bs[SB][ldsc0]);                                       \
        gload_lds16(hy + (size_t)(col0 + r1s) * 256 + (kt) * 32 + q1 * 8,         \
                    (void*)&Bs[SB][ldsc1]);                                       \
    } while (0)

    short8 a[4], b[4];
    // read fragment: row rt, k-chunk lk -> LDS chunk c = lk ^ f(rt)
#define RD_A(BUF, H)                                                              \
    { _Pragma("unroll")                                                           \
      for (int mi = 0; mi < 4; ++mi) {                                            \
          int rt = wm * 128 + (H) * 64 + mi * 16 + lm;                            \
          a[mi] = *(const short8*)&As[BUF][rt * 32 + ((lk ^ FXOR(rt)) << 3)];     \
      } }
#define RD_B(BUF)                                                                 \
    { _Pragma("unroll")                                                           \
      for (int ni = 0; ni < 4; ++ni) {                                            \
          int rt = wn * 64 + ni * 16 + lm;                                        \
          b[ni] = *(const short8*)&Bs[BUF][rt * 32 + ((lk ^ FXOR(rt)) << 3)];     \
      } }
#define MM(BASE)                                                                  \
    { __builtin_amdgcn_s_setprio(1);                                              \
      _Pragma("unroll")                                                           \
      for (int mi = 0; mi < 4; ++mi)                                              \
          _Pragma("unroll")                                                       \
          for (int ni = 0; ni < 4; ++ni)                                          \
              acc[(BASE) + mi][ni] = __builtin_amdgcn_mfma_f32_16x16x32_bf16(     \
                  a[mi], b[ni], acc[(BASE) + mi][ni], 0, 0, 0);                   \
      __builtin_amdgcn_s_setprio(0); }

#define BAR do { asm volatile("" ::: "memory"); __builtin_amdgcn_s_barrier();     \
                 asm volatile("" ::: "memory"); } while (0)
#define WAITV(N) asm volatile("s_waitcnt vmcnt(" N ")" ::: "memory")

    // Tile T (buffer T&3). ph0: read Alo+B, stage A(T+3); MFMA lo.
    //                      ph1: read Ahi,   stage B(T+3); WAITV gates tile T+1; MFMA hi.
#define TILE(T, DO_STAGE, HAS_WAIT, WS)                                           \
    {                                                                             \
        RD_A((T) & 3, 0) RD_B((T) & 3)                                            \
        if (DO_STAGE) STAGE_A(((T) + 3) & 3, (T) + 3);                            \
        BAR;                                                                      \
        MM(0) BAR;                                                                \
        RD_A((T) & 3, 1)                                                          \
        if (DO_STAGE) STAGE_B(((T) + 3) & 3, (T) + 3);                            \
        if (HAS_WAIT) WAITV(WS);                                                  \
        BAR;                                                                      \
        MM(4) BAR;                                                                \
    }

    // prologue: prime tiles 0,1,2 (12 loads/thread); gate tile 0.
    STAGE_A(0, 0); STAGE_B(0, 0);
    STAGE_A(1, 1); STAGE_B(1, 1);
    STAGE_A(2, 2); STAGE_B(2, 2);
    WAITV("8");
    BAR;

    TILE(0, 1, 1, "8")
    TILE(1, 1, 1, "8")
    TILE(2, 1, 1, "8")
    TILE(3, 1, 1, "8")
    TILE(4, 1, 1, "8")
    TILE(5, 0, 1, "4")
    TILE(6, 0, 1, "0")
    TILE(7, 0, 0, "0")

#undef TILE
#undef STAGE_A
#undef STAGE_B
#undef RD_A
#undef RD_B
#undef MM
#undef BAR
#undef WAITV
#undef FXOR

    // Epilogue: exp + row sums (DPP reduce). C/D: col = lane&15, row = (lane>>4)*4 + reg.
    const int lg = lane >> 4;
    #pragma unroll
    for (int mi = 0; mi < 8; ++mi) {
        float rs[4] = {0.f, 0.f, 0.f, 0.f};
        #pragma unroll
        for (int ni = 0; ni < 4; ++ni) {
            #pragma unroll
            for (int r = 0; r < 4; ++r) rs[r] += __expf(acc[mi][ni][r]);
        }
        #pragma unroll
        for (int r = 0; r < 4; ++r) {
            float s = reduce16(rs[r]);
            if (lm == 0)
                unsafeAtomicAdd(&row_acc[row0 + wm * 128 + mi * 16 + lg * 4 + r], s);
        }
    }
}

// Kernel 3: out = clip(log(acc) - g - log(B), -5, 15)
__global__ void finalize_kernel(const float* __restrict__ acc, const float* __restrict__ g,
                                float* __restrict__ out, int B) {
    int i = blockIdx.x * 256 + threadIdx.x;
    if (i < B) {
        float v = logf(acc[i]) - g[i] - logf((float)B);
        out[i] = fminf(fmaxf(v, -5.f), 15.f);
    }
}

extern "C" void kernel_launch(void* const* d_in, const int* in_sizes, int n_in,
                              void* d_out, int out_size, void* d_ws, size_t ws_size,
                              hipStream_t stream) {
    const float* z       = (const float*)d_in[0];
    const float* t       = (const float*)d_in[1];
    const float* e       = (const float*)d_in[2];
    const float* log_tau = (const float*)d_in[3];
    const float* E       = (const float*)d_in[4];
    const float* L       = (const float*)d_in[5];
    float* out = (float*)d_out;

    const int B = in_sizes[1];   // 8192
    const int m = in_sizes[5];   // 256

    char* w = (char*)d_ws;
    __hip_bfloat16* hz = (__hip_bfloat16*)w;                 // B*m bf16
    __hip_bfloat16* hy = hz + (size_t)B * m;                 // B*m bf16
    float* ST   = (float*)(hy + (size_t)B * m);              // m*m f32
    float* g    = ST + (size_t)m * m;                        // B f32
    float* acc  = g + B;                                     // B f32

    suffix_kernel<<<m, 256, 0, stream>>>(E, ST, m);
    prep_kernel<<<B / 16, 256, 0, stream>>>(z, t, e, log_tau, E, L, ST, hz, hy, g, acc, B, m);
    dim3 grid2(32, 32);
    gemm_lse_kernel<<<grid2, 512, 0, stream>>>(hz, hy, acc, B, m);
    finalize_kernel<<<(B + 255) / 256, 256, 0, stream>>>(acc, g, out, B);
}